// Round 1
// baseline (360.082 us; speedup 1.0000x reference)
//
#include <hip/hip_runtime.h>
#include <math.h>

#define BB 8
#define CH 128
#define HH 64
#define WW 64
#define OC 128
#define NPIX (HH*WW)          // 4096

// workspace layout (in floats)
#define XT_OFF   0
#define XT_SZ    (BB*NPIX*CH)             // 4,194,304
#define OM_OFF   (XT_OFF + XT_SZ)
#define OMS      28
#define OM_SZ    (BB*NPIX*OMS)            // 917,504
#define WT_OFF   (OM_OFF + OM_SZ)
#define WT_SZ    (9*CH*OC)                // 147,456
#define W27_OFF  (WT_OFF + WT_SZ)
#define W27_SZ   (9*CH*32)                // 36,864

// ---------------------------------------------------------------------------
// Kernel 1: NCHW -> NHWC transpose of x, one (b,h) row per block.
__global__ __launch_bounds__(256) void k_transpose(const float* __restrict__ x,
                                                   float* __restrict__ xt) {
    __shared__ float tile[128][65];
    int bh = blockIdx.x;                       // b*64 + h
    const float* src = x + (size_t)(bh >> 6) * (CH * NPIX) + (size_t)(bh & 63) * WW;
    int t = threadIdx.x;
#pragma unroll
    for (int it = 0; it < 32; ++it) {
        int idx = it * 256 + t;                // idx = c*64 + w
        tile[idx >> 6][idx & 63] = src[(idx >> 6) * NPIX + (idx & 63)];
    }
    __syncthreads();
    float* dst = xt + (size_t)bh * (WW * CH);
#pragma unroll
    for (int it = 0; it < 32; ++it) {
        int idx = it * 256 + t;                // idx = w*128 + c
        dst[idx] = tile[idx & 127][idx >> 7];
    }
}

// ---------------------------------------------------------------------------
// Kernel 2: repack weights: wt[k2][c][oc] ; w27[k2][c][oc<32] (18 off + 9 mask + pad)
__global__ __launch_bounds__(256) void k_reorder_w(const float* __restrict__ weight,
                                                   const float* __restrict__ offw,
                                                   const float* __restrict__ maskw,
                                                   float* __restrict__ wt,
                                                   float* __restrict__ w27) {
    int idx = blockIdx.x * 256 + threadIdx.x;
    if (idx < WT_SZ) {
        int k2 = idx >> 14;                    // / (128*128)
        int r  = idx & 16383;
        int c  = r >> 7;
        int oc = r & 127;
        wt[idx] = weight[(oc * CH + c) * 9 + k2];
    } else {
        int j  = idx - WT_SZ;                  // < 36864
        int k2 = j >> 12;                      // / 4096
        int r  = j & 4095;
        int c  = r >> 5;
        int oc = r & 31;
        float v = 0.f;
        if (oc < 18)      v = offw[(oc * CH + c) * 9 + k2];
        else if (oc < 27) v = maskw[((oc - 18) * CH + c) * 9 + k2];
        w27[j] = v;
    }
}

// ---------------------------------------------------------------------------
// Kernel 3: offset+mask conv (27 channels) as tiled GEMM; sigmoid fused.
// One block per (b, ho) row: M=32(27), N=64 px, K=1152.
__global__ __launch_bounds__(256) void k_omconv(const float* __restrict__ xt,
                                                const float* __restrict__ w27,
                                                const float* __restrict__ offb,
                                                const float* __restrict__ maskb,
                                                float* __restrict__ om) {
    __shared__ __align__(16) float patch[CH][65];
    __shared__ __align__(16) float wsh[CH][36];
    int blk = blockIdx.x;
    int b = blk >> 6, ho = blk & 63;
    int t = threadIdx.x;
    int og = t & 7, pg = t >> 3;               // oc = og*4+j ; px = pg + 32*i
    float acc[4][2] = {};
    const float* xb = xt + (size_t)b * (NPIX * CH);
    for (int k2 = 0; k2 < 9; ++k2) {
        int ki = k2 / 3, kj = k2 - ki * 3;
        int y = ho + ki - 1;
        bool yok = (unsigned)y < 64u;
        __syncthreads();
#pragma unroll
        for (int it = 0; it < 4; ++it) {       // stage 128x32 weights
            int i4 = it * 256 + t;
            int oc4 = i4 & 7, cc = i4 >> 3;
            *(float4*)&wsh[cc][oc4 * 4] = *(const float4*)&w27[(k2 * CH + cc) * 32 + oc4 * 4];
        }
#pragma unroll
        for (int it = 0; it < 8; ++it) {       // stage patch 128c x 64px
            int i4 = it * 256 + t;
            int c4 = i4 & 31, px = i4 >> 5;
            int xx = px + kj - 1;
            float4 v = {0.f, 0.f, 0.f, 0.f};
            if (yok && (unsigned)xx < 64u)
                v = *(const float4*)&xb[(y * 64 + xx) * CH + c4 * 4];
            patch[c4 * 4 + 0][px] = v.x;
            patch[c4 * 4 + 1][px] = v.y;
            patch[c4 * 4 + 2][px] = v.z;
            patch[c4 * 4 + 3][px] = v.w;
        }
        __syncthreads();
        for (int cc = 0; cc < CH; ++cc) {
            float4 w4 = *(const float4*)&wsh[cc][og * 4];
            float p0 = patch[cc][pg];
            float p1 = patch[cc][pg + 32];
            acc[0][0] += w4.x * p0; acc[0][1] += w4.x * p1;
            acc[1][0] += w4.y * p0; acc[1][1] += w4.y * p1;
            acc[2][0] += w4.z * p0; acc[2][1] += w4.z * p1;
            acc[3][0] += w4.w * p0; acc[3][1] += w4.w * p1;
        }
    }
    float* omb = om + ((size_t)(b * NPIX) + ho * 64) * OMS;
#pragma unroll
    for (int j = 0; j < 4; ++j) {
        int oc = og * 4 + j;
        if (oc >= 27) continue;
#pragma unroll
        for (int i = 0; i < 2; ++i) {
            int px = pg + 32 * i;
            float v = acc[j][i];
            if (oc < 18) {
                v += offb[oc];
            } else {
                v += maskb[oc - 18];
                v = 1.f / (1.f + expf(-v));
            }
            omb[px * OMS + oc] = v;
        }
    }
}

// ---------------------------------------------------------------------------
// Kernel 4: main deformable conv. One block per (b, ho) row.
// Per k2: bilinear params per px (validity+mask folded into corner weights),
// then per c-half: stage weights, gather cols[c][px], register-tiled GEMM.
__global__ __launch_bounds__(256) void k_main(const float* __restrict__ xt,
                                              const float* __restrict__ wt,
                                              const float* __restrict__ om,
                                              float* __restrict__ out) {
    __shared__ __align__(16) float cols[64][65];
    __shared__ __align__(16) float wsh[64][132];
    __shared__ float4 pw[64];
    __shared__ int4   pb[64];
    int blk = blockIdx.x;
    int b = blk >> 6, ho = blk & 63;
    int t = threadIdx.x;
    int og = t & 15, pg = t >> 4;              // oc = og*8+j ; px = pg + 16*i
    float acc[8][4] = {};
    const float* ombase = om + ((size_t)(b * NPIX) + ho * 64) * OMS;
    const float* xb = xt + (size_t)b * (NPIX * CH);
    for (int k2 = 0; k2 < 9; ++k2) {
        int ki = k2 / 3, kj = k2 - ki * 3;
        __syncthreads();
        if (t < 64) {
            int px = t;
            float dy = ombase[px * OMS + 2 * k2];
            float dx = ombase[px * OMS + 2 * k2 + 1];
            float m  = ombase[px * OMS + 18 + k2];
            float py  = (float)(ho + ki - 1) + dy;
            float pxx = (float)(px + kj - 1) + dx;
            float y0f = floorf(py), x0f = floorf(pxx);
            float ly = py - y0f, lx = pxx - x0f;
            int y0 = (int)y0f, x0 = (int)x0f;
            int y1 = y0 + 1, x1 = x0 + 1;
            bool vy0 = (unsigned)y0 < 64u, vy1 = (unsigned)y1 < 64u;
            bool vx0 = (unsigned)x0 < 64u, vx1 = (unsigned)x1 < 64u;
            float w00 = (vy0 && vx0) ? (1.f - ly) * (1.f - lx) * m : 0.f;
            float w01 = (vy0 && vx1) ? (1.f - ly) * lx * m : 0.f;
            float w10 = (vy1 && vx0) ? ly * (1.f - lx) * m : 0.f;
            float w11 = (vy1 && vx1) ? ly * lx * m : 0.f;
            int yc0 = min(max(y0, 0), 63), yc1 = min(max(y1, 0), 63);
            int xc0 = min(max(x0, 0), 63), xc1 = min(max(x1, 0), 63);
            pw[px] = make_float4(w00, w01, w10, w11);
            pb[px] = make_int4((yc0 * 64 + xc0) * CH, (yc0 * 64 + xc1) * CH,
                               (yc1 * 64 + xc0) * CH, (yc1 * 64 + xc1) * CH);
        }
        __syncthreads();
        for (int half = 0; half < 2; ++half) {
            int c0 = half << 6;
            if (half) __syncthreads();
#pragma unroll
            for (int it = 0; it < 8; ++it) {   // stage 64c x 128oc weights
                int i4 = it * 256 + t;
                int oc4 = i4 & 31, cc = i4 >> 5;
                *(float4*)&wsh[cc][oc4 * 4] =
                    *(const float4*)&wt[((k2 * CH) + c0 + cc) * OC + oc4 * 4];
            }
            {
                int cc = t & 63, pxg = t >> 6;
#pragma unroll 4
                for (int i = 0; i < 16; ++i) {
                    int px = pxg + 4 * i;
                    float4 w = pw[px];
                    int4 bs = pb[px];
                    float v = w.x * xb[bs.x + c0 + cc]
                            + w.y * xb[bs.y + c0 + cc]
                            + w.z * xb[bs.z + c0 + cc]
                            + w.w * xb[bs.w + c0 + cc];
                    cols[cc][px] = v;
                }
            }
            __syncthreads();
            for (int cc = 0; cc < 64; ++cc) {
                float4 wa = *(const float4*)&wsh[cc][og * 8];
                float4 wb = *(const float4*)&wsh[cc][og * 8 + 4];
                float p0 = cols[cc][pg];
                float p1 = cols[cc][pg + 16];
                float p2 = cols[cc][pg + 32];
                float p3 = cols[cc][pg + 48];
                acc[0][0] += wa.x * p0; acc[0][1] += wa.x * p1; acc[0][2] += wa.x * p2; acc[0][3] += wa.x * p3;
                acc[1][0] += wa.y * p0; acc[1][1] += wa.y * p1; acc[1][2] += wa.y * p2; acc[1][3] += wa.y * p3;
                acc[2][0] += wa.z * p0; acc[2][1] += wa.z * p1; acc[2][2] += wa.z * p2; acc[2][3] += wa.z * p3;
                acc[3][0] += wa.w * p0; acc[3][1] += wa.w * p1; acc[3][2] += wa.w * p2; acc[3][3] += wa.w * p3;
                acc[4][0] += wb.x * p0; acc[4][1] += wb.x * p1; acc[4][2] += wb.x * p2; acc[4][3] += wb.x * p3;
                acc[5][0] += wb.y * p0; acc[5][1] += wb.y * p1; acc[5][2] += wb.y * p2; acc[5][3] += wb.y * p3;
                acc[6][0] += wb.z * p0; acc[6][1] += wb.z * p1; acc[6][2] += wb.z * p2; acc[6][3] += wb.z * p3;
                acc[7][0] += wb.w * p0; acc[7][1] += wb.w * p1; acc[7][2] += wb.w * p2; acc[7][3] += wb.w * p3;
            }
        }
    }
    float* ob = out + ((size_t)b * OC * NPIX) + ho * 64;
#pragma unroll
    for (int j = 0; j < 8; ++j) {
        int oc = og * 8 + j;
#pragma unroll
        for (int i = 0; i < 4; ++i) {
            int px = pg + 16 * i;
            ob[(size_t)oc * NPIX + px] = acc[j][i];
        }
    }
}

// ---------------------------------------------------------------------------
extern "C" void kernel_launch(void* const* d_in, const int* in_sizes, int n_in,
                              void* d_out, int out_size, void* d_ws, size_t ws_size,
                              hipStream_t stream) {
    const float* x     = (const float*)d_in[0];
    const float* wgt   = (const float*)d_in[1];
    const float* offw  = (const float*)d_in[2];
    const float* offb  = (const float*)d_in[3];
    const float* maskw = (const float*)d_in[4];
    const float* maskb = (const float*)d_in[5];
    float* out = (float*)d_out;
    float* wsp = (float*)d_ws;
    float* xt  = wsp + XT_OFF;
    float* om  = wsp + OM_OFF;
    float* wt  = wsp + WT_OFF;
    float* w27 = wsp + W27_OFF;

    hipLaunchKernelGGL(k_transpose, dim3(BB * HH), dim3(256), 0, stream, x, xt);
    hipLaunchKernelGGL(k_reorder_w, dim3((WT_SZ + W27_SZ) / 256), dim3(256), 0, stream,
                       wgt, offw, maskw, wt, w27);
    hipLaunchKernelGGL(k_omconv, dim3(BB * HH), dim3(256), 0, stream,
                       xt, w27, offb, maskb, om);
    hipLaunchKernelGGL(k_main, dim3(BB * HH), dim3(256), 0, stream, xt, wt, om, out);
}